// Round 10
// baseline (308.886 us; speedup 1.0000x reference)
//
#include <hip/hip_runtime.h>

constexpr int C  = 256;
constexpr int H  = 224;
constexpr int W  = 224;
constexpr int HW = H * W;               // 50176
constexpr int PIX = 256;                // pixels per block (64 float4 columns)
constexpr int THREADS = 1024;
constexpr int TILES_PER_B = HW / PIX;   // 196 (exact)
constexpr int BATCH = 16;

typedef float f32x4 __attribute__((ext_vector_type(4)));

__global__ __launch_bounds__(THREADS, 4)
void fused_sigmoid_border_scale(const float* __restrict__ x,
                                const float* __restrict__ wv,
                                const float* __restrict__ bv,
                                float* __restrict__ out)
{
    __shared__ f32x4 pw[16][64];   // [wave][col] partial sums, 16 KB

    const int t    = threadIdx.x;
    const int q    = t & 63;       // float4 column (pixels q*4..q*4+3) — spans the wave
    const int c0   = t >> 6;       // channel subgroup 0..15 — WAVE-UNIFORM
    const int blk  = blockIdx.x;
    const int b    = blk / TILES_PER_B;
    const int hw0  = (blk - b * TILES_PER_B) * PIX;

    const float* xb = x   + (size_t)b * C * HW + hw0 + q * 4;
    float*       ob = out + (size_t)b * C * HW + hw0 + q * 4;

    // ---- load 16 channels x 4 pixels into registers (1x1024B segment/instr) ----
    f32x4 v[16];
    #pragma unroll
    for (int k = 0; k < 16; ++k) {
        const int c = k * 16 + c0;
        v[k] = __builtin_nontemporal_load(
            reinterpret_cast<const f32x4*>(xb + (size_t)c * HW));
    }

    // ---- per-thread partial dot over its 16 channels (weights are scalar loads) ----
    f32x4 acc = (f32x4)(0.f);
    #pragma unroll
    for (int k = 0; k < 16; ++k) {
        const float wk = wv[k * 16 + c0];   // wave-uniform -> SGPR
        acc.x = fmaf(v[k].x, wk, acc.x);
        acc.y = fmaf(v[k].y, wk, acc.y);
        acc.z = fmaf(v[k].z, wk, acc.z);
        acc.w = fmaf(v[k].w, wk, acc.w);
    }

    // keep the tile live in VGPRs — forbid load rematerialization
    #pragma unroll
    for (int k = 0; k < 16; ++k)
        asm volatile("" : "+v"(v[k]));

    // ---- cross-wave reduce: no shfl needed (channel group == wave) ----
    pw[c0][q] = acc;
    __syncthreads();               // the ONLY barrier

    // ---- every thread: combine 16 wave-partials + sigmoid + border ----
    f32x4 s4 = (f32x4)(0.f);
    #pragma unroll
    for (int w16 = 0; w16 < 16; ++w16) s4 += pw[w16][q];
    const float b0 = bv[0];
    f32x4 comb;
    #pragma unroll
    for (int j = 0; j < 4; ++j) {
        const float att = 1.0f / (1.0f + expf(-(s4[j] + b0)));
        const int hw = hw0 + q * 4 + j;
        const int h  = hw / W;
        const int w  = hw - h * W;
        const bool border = (h == 0) | (h == H - 1) | (w == 0) | (w == W - 1);
        comb[j] = att * (border ? 2.0f : 1.0f);
    }

    // ---- scale registers and store (1x1024B segment/instr) ----
    #pragma unroll
    for (int k = 0; k < 16; ++k) {
        const int c = k * 16 + c0;
        __builtin_nontemporal_store(v[k] * comb,
            reinterpret_cast<f32x4*>(ob + (size_t)c * HW));
    }
}

extern "C" void kernel_launch(void* const* d_in, const int* in_sizes, int n_in,
                              void* d_out, int out_size, void* d_ws, size_t ws_size,
                              hipStream_t stream) {
    const float* x  = (const float*)d_in[0];
    const float* wv = (const float*)d_in[1];
    const float* bv = (const float*)d_in[2];
    float* out = (float*)d_out;

    dim3 grid(BATCH * TILES_PER_B);   // 3136 blocks, one 256-pixel tile each
    fused_sigmoid_border_scale<<<grid, THREADS, 0, stream>>>(x, wv, bv, out);
}

// Round 11
// 304.672 us; speedup vs baseline: 1.0138x; 1.0138x over previous
//
#include <hip/hip_runtime.h>

constexpr int C  = 256;
constexpr int H  = 224;
constexpr int W  = 224;
constexpr int HW = H * W;               // 50176
constexpr int PIX = 128;                // pixels per block (32 float4 columns)
constexpr int THREADS = 512;
constexpr int TILES_PER_B = HW / PIX;   // 392 (exact)
constexpr int BATCH = 16;

typedef float f32x4 __attribute__((ext_vector_type(4)));

__global__ __launch_bounds__(THREADS, 4)
void fused_sigmoid_border_scale(const float* __restrict__ x,
                                const float* __restrict__ wv,
                                const float* __restrict__ bv,
                                float* __restrict__ out)
{
    __shared__ f32x4 pw[8][32];    // [wave][col] partial sums, 4 KB

    const int t    = threadIdx.x;
    const int q    = t & 31;       // float4 column (pixels q*4..q*4+3)
    const int c0   = t >> 5;       // channel subgroup 0..15 (wave w covers 2w,2w+1)
    const int wave = t >> 6;
    const int blk  = blockIdx.x;
    const int b    = blk / TILES_PER_B;
    const int hw0  = (blk - b * TILES_PER_B) * PIX;

    const float* xb = x   + (size_t)b * C * HW + hw0 + q * 4;
    float*       ob = out + (size_t)b * C * HW + hw0 + q * 4;

    // ---- load 16 channels x 4 pixels into registers (2x512B segments/instr) ----
    f32x4 v[16];
    #pragma unroll
    for (int k = 0; k < 16; ++k) {
        const int c = k * 16 + c0;
        v[k] = __builtin_nontemporal_load(
            reinterpret_cast<const f32x4*>(xb + (size_t)c * HW));
    }

    // ---- per-thread partial dot over its 16 channels ----
    f32x4 acc = (f32x4)(0.f);
    #pragma unroll
    for (int k = 0; k < 16; ++k) {
        const float wk = wv[k * 16 + c0];
        acc.x = fmaf(v[k].x, wk, acc.x);
        acc.y = fmaf(v[k].y, wk, acc.y);
        acc.z = fmaf(v[k].z, wk, acc.z);
        acc.w = fmaf(v[k].w, wk, acc.w);
    }

    // keep the tile live in VGPRs — forbid load rematerialization
    #pragma unroll
    for (int k = 0; k < 16; ++k)
        asm volatile("" : "+v"(v[k]));

    // ---- fold the wave's two c0-subgroups (lane bit 5) ----
    acc.x += __shfl_xor(acc.x, 32);
    acc.y += __shfl_xor(acc.y, 32);
    acc.z += __shfl_xor(acc.z, 32);
    acc.w += __shfl_xor(acc.w, 32);
    if ((t & 63) < 32) pw[wave][q] = acc;   // one f32x4 per col per wave
    __syncthreads();                        // the ONLY barrier

    // ---- every thread: combine 8 wave-partials + sigmoid + border ----
    const f32x4 s4 = ((pw[0][q] + pw[1][q]) + (pw[2][q] + pw[3][q]))
                   + ((pw[4][q] + pw[5][q]) + (pw[6][q] + pw[7][q]));
    const float b0 = bv[0];
    f32x4 comb;
    #pragma unroll
    for (int j = 0; j < 4; ++j) {
        const float att = 1.0f / (1.0f + expf(-(s4[j] + b0)));
        const int hw = hw0 + q * 4 + j;
        const int h  = hw / W;
        const int w  = hw - h * W;
        const bool border = (h == 0) | (h == H - 1) | (w == 0) | (w == W - 1);
        comb[j] = att * (border ? 2.0f : 1.0f);
    }

    // ---- scale registers and store (2x512B segments/instr) ----
    #pragma unroll
    for (int k = 0; k < 16; ++k) {
        const int c = k * 16 + c0;
        __builtin_nontemporal_store(v[k] * comb,
            reinterpret_cast<f32x4*>(ob + (size_t)c * HW));
    }
}

extern "C" void kernel_launch(void* const* d_in, const int* in_sizes, int n_in,
                              void* d_out, int out_size, void* d_ws, size_t ws_size,
                              hipStream_t stream) {
    const float* x  = (const float*)d_in[0];
    const float* wv = (const float*)d_in[1];
    const float* bv = (const float*)d_in[2];
    float* out = (float*)d_out;

    dim3 grid(BATCH * TILES_PER_B);   // 6272 blocks, one 128-pixel tile each
    fused_sigmoid_border_scale<<<grid, THREADS, 0, stream>>>(x, wv, bv, out);
}